// Round 2
// baseline (232.791 us; speedup 1.0000x reference)
//
#include <hip/hip_runtime.h>
#include <cstdint>
#include <cstddef>

// Exact radix select on order-transformed x bits among t<0 entries
// (t = -1 exactly => negative_loss = softplus(x), strictly increasing in x).
//
// R6 structure (fixes R5's 47 µs atomic-serialized k2_hist2):
//   k1:        82 MB read; 2048-bin LDS hist (bits[31:21]); compacts ALL
//              negatives' u into per-wave cand1 segments (13.7 MB, no atomics);
//              emits 2-bit class map (2.56 MB) for k_final.
//   s1:        1 block — pick 11-bit prefix1 + rank k1rem.
//   k2_compact:reads cand1 (13.7 MB), keeps prefix1 matches (~75k, ~300 KB)
//              into per-wave cand2 segments. ZERO global atomics (R5's k2 did
//              75k device atomics onto a 4 KB histogram -> 64-line ping-pong,
//              ~35 ns/RMW serialized = 47 µs. Scattered/LDS atomics are fine;
//              small-footprint global histograms are not.)
//   s2_final:  1 block, 1024 thr — two LDS-histogram passes over the ~300 KB
//              survivors: bits[20:10] (2048 bins) then bits[9:0] (1024 bins)
//              -> exact u_kth + precise loss threshold. Replaces s2+k3+s3.
//   k_final:   x + cmap read (no t re-read), fast __expf/__logf values,
//              bit-exact mask, precise re-check only in 256-ulp guard band.
//
// ws layout:
//   [0     ..  8192)   hist1  (2048 u32)  bits [31:21]
//   [20480 .. 20544)   SelState
//   [24576 .. 40960)   wvcnt  (<=4096 u32, per-wave cand1 counts)
//   [40960 .. +n/4)    cmap   (2-bit class per element, byte per quad)
//   [A=align256 ..)    cand1  (nseg * segw u32)
//   [B=A+cand1 ..)     cand2  (nseg * segw u32)   (~42 MB each @ n=10.24M)
//   wvcnt2 lives at ws+12288 (4096 u32 would overlap hist area — so placed
//   after cand2; see launch code).

struct SelState {
    uint32_t prefix1;  // 11-bit level-1 prefix (bits 31:21)
    uint32_t k1rem;    // remaining rank within level-1 bin (1-based)
    uint32_t prefix2;  // unused on this path (kept for layout stability)
    uint32_t k2rem;    // unused
    uint32_t u_kth;    // final: transformed bits of k-th largest x
    float    thr_nl;   // final: precise loss-space threshold
    uint32_t done;
};

#define GUARD 256u

__device__ __forceinline__ uint32_t xform(uint32_t b) {
    return ((int32_t)b < 0) ? ~b : (b | 0x80000000u);
}
__device__ __forceinline__ float unxform(uint32_t u) {
    uint32_t b = (u & 0x80000000u) ? (u ^ 0x80000000u) : ~u;
    return __uint_as_float(b);
}
// precise chain — matches reference fp32 semantics; used only for the
// threshold value and the rare guard-band compare.
__device__ __forceinline__ float neg_loss_precise(float x, float t) {
#pragma clang fp contract(off)
    return (fmaxf(-x, 0.0f) - x * t) + log1pf(expf(-fabsf(x)));
}

// wave-wide inclusive scan -> exclusive offset + total (64 lanes)
__device__ __forceinline__ void wscan(uint32_t m, int lane, uint32_t& excl, uint32_t& tot) {
    uint32_t inc = m;
#pragma unroll
    for (int d = 1; d < 64; d <<= 1) {
        uint32_t v = __shfl_up(inc, (unsigned)d, 64);
        if (lane >= d) inc += v;
    }
    excl = inc - m;
    tot = __shfl(inc, 63, 64);
}

// per-quad: u values (0 if not negative), class byte, LDS histogram
__device__ __forceinline__ uint32_t quad_u_cls(uint32_t* my, float4 xv, float4 tv,
        uint32_t& u0, uint32_t& u1, uint32_t& u2, uint32_t& u3) {
    u0 = (tv.x < 0.0f) ? xform(__float_as_uint(xv.x)) : 0u;
    u1 = (tv.y < 0.0f) ? xform(__float_as_uint(xv.y)) : 0u;
    u2 = (tv.z < 0.0f) ? xform(__float_as_uint(xv.z)) : 0u;
    u3 = (tv.w < 0.0f) ? xform(__float_as_uint(xv.w)) : 0u;
    uint32_t cls = ((tv.x > 0.0f) ? 1u : ((tv.x < 0.0f) ? 2u : 0u))
                 | (((tv.y > 0.0f) ? 1u : ((tv.y < 0.0f) ? 2u : 0u)) << 2)
                 | (((tv.z > 0.0f) ? 1u : ((tv.z < 0.0f) ? 2u : 0u)) << 4)
                 | (((tv.w > 0.0f) ? 1u : ((tv.w < 0.0f) ? 2u : 0u)) << 6);
    if (u0) atomicAdd(&my[u0 >> 21], 1u);
    if (u1) atomicAdd(&my[u1 >> 21], 1u);
    if (u2) atomicAdd(&my[u2 >> 21], 1u);
    if (u3) atomicAdd(&my[u3 >> 21], 1u);
    return cls;
}

// ---------- k1: 11-bit LDS histogram + negative compaction + class map ----------
__global__ __launch_bounds__(256) void k1_hist(
        const float* __restrict__ x, const float* __restrict__ t,
        uint32_t* __restrict__ hist1, uint32_t* __restrict__ cand1,
        uint32_t* __restrict__ wvcnt, uint8_t* __restrict__ cmap,
        int n, int segw) {
    __shared__ uint32_t lh[2 * 2049];   // 2-way replicated (+1 pad)
    for (int j = threadIdx.x; j < 2 * 2049; j += 256) lh[j] = 0;
    __syncthreads();
    uint32_t* my = &lh[(threadIdx.x & 1) * 2049];

    const float4* x4 = (const float4*)x;
    const float4* t4 = (const float4*)t;
    const int n4 = n >> 2;
    const int S = gridDim.x * 256;
    const int lane = threadIdx.x & 63;
    const int wid  = threadIdx.x >> 6;
    uint32_t* wseg = cand1 + (size_t)(blockIdx.x * 4 + wid) * (size_t)segw;
    uint32_t wcur = 0;   // wave-uniform segment cursor (no atomics)

    // block-uniform count of full 4x-unrolled batches (appends use wave-wide
    // shfl scans, so the unrolled loop must be wave-uniform)
    int M4 = 0;
    {
        long rem = (long)n4 - 1 - (long)(blockIdx.x * 256 + 255);
        if (rem >= 0) {
            long T = rem / S;
            if (T >= 3) M4 = (int)((T - 3) / 4 + 1);
        }
    }
    int i = blockIdx.x * 256 + threadIdx.x;

    for (int b = 0; b < M4; ++b, i += 4 * S) {   // 8 independent 16B loads in flight
        float4 xa = x4[i], xb = x4[i + S], xc = x4[i + 2 * S], xd = x4[i + 3 * S];
        float4 ta = t4[i], tb = t4[i + S], tc = t4[i + 2 * S], td = t4[i + 3 * S];
        uint32_t u0, u1, u2, u3, u4_, u5, u6, u7, u8, u9, uA, uB, uC, uD, uE, uF;
        uint32_t ca = quad_u_cls(my, xa, ta, u0, u1, u2, u3);
        uint32_t cb = quad_u_cls(my, xb, tb, u4_, u5, u6, u7);
        uint32_t cc = quad_u_cls(my, xc, tc, u8, u9, uA, uB);
        uint32_t cd = quad_u_cls(my, xd, td, uC, uD, uE, uF);
        cmap[i]         = (uint8_t)ca;
        cmap[i + S]     = (uint8_t)cb;
        cmap[i + 2 * S] = (uint8_t)cc;
        cmap[i + 3 * S] = (uint8_t)cd;
        uint32_t m = (u0 != 0) + (u1 != 0) + (u2 != 0) + (u3 != 0)
                   + (u4_ != 0) + (u5 != 0) + (u6 != 0) + (u7 != 0)
                   + (u8 != 0) + (u9 != 0) + (uA != 0) + (uB != 0)
                   + (uC != 0) + (uD != 0) + (uE != 0) + (uF != 0);
        uint32_t excl, tot;
        wscan(m, lane, excl, tot);
        uint32_t p = wcur + excl;
        if (u0)  wseg[p++] = u0;
        if (u1)  wseg[p++] = u1;
        if (u2)  wseg[p++] = u2;
        if (u3)  wseg[p++] = u3;
        if (u4_) wseg[p++] = u4_;
        if (u5)  wseg[p++] = u5;
        if (u6)  wseg[p++] = u6;
        if (u7)  wseg[p++] = u7;
        if (u8)  wseg[p++] = u8;
        if (u9)  wseg[p++] = u9;
        if (uA)  wseg[p++] = uA;
        if (uB)  wseg[p++] = uB;
        if (uC)  wseg[p++] = uC;
        if (uD)  wseg[p++] = uD;
        if (uE)  wseg[p++] = uE;
        if (uF)  wseg[p++] = uF;
        wcur += tot;
    }

    // masked single-quad remainder (wave-uniform loop via __any)
    for (; __any(i < n4); i += S) {
        const bool act = i < n4;
        float4 xa = act ? x4[i] : make_float4(0.f, 0.f, 0.f, 0.f);
        float4 ta = act ? t4[i] : make_float4(0.f, 0.f, 0.f, 0.f);
        uint32_t u0, u1, u2, u3;
        uint32_t ca = quad_u_cls(my, xa, ta, u0, u1, u2, u3);
        if (act) cmap[i] = (uint8_t)ca;
        uint32_t m = (u0 != 0) + (u1 != 0) + (u2 != 0) + (u3 != 0);
        uint32_t excl, tot;
        wscan(m, lane, excl, tot);
        uint32_t p = wcur + excl;
        if (u0) wseg[p++] = u0;
        if (u1) wseg[p++] = u1;
        if (u2) wseg[p++] = u2;
        if (u3) wseg[p++] = u3;
        wcur += tot;
    }

    // n % 4 tail (block 0 only; <4 elems; no cmap — k_final reads t for tail)
    if (blockIdx.x == 0) {
        int j = (n4 << 2) + threadIdx.x;
        const bool act = j < n;
        float xx = act ? x[j] : 0.0f;
        float tt = act ? t[j] : 0.0f;
        uint32_t u0 = (tt < 0.0f) ? xform(__float_as_uint(xx)) : 0u;
        if (u0) atomicAdd(&my[u0 >> 21], 1u);
        uint32_t excl, tot;
        wscan(u0 != 0 ? 1u : 0u, lane, excl, tot);
        if (u0) wseg[wcur + excl] = u0;
        wcur += tot;
    }

    if (lane == 0) wvcnt[blockIdx.x * 4 + wid] = wcur;

    __syncthreads();
    for (int b2 = threadIdx.x; b2 < 2048; b2 += 256) {
        uint32_t c = lh[b2] + lh[2049 + b2];
        if (c) atomicAdd(&hist1[b2], c);
    }
}

// ---------------- s1: 1 block, pick 11-bit prefix ----------------
__global__ __launch_bounds__(256) void s1_scan(
        const uint32_t* __restrict__ hist1, SelState* __restrict__ st,
        const int* __restrict__ kptr) {
    __shared__ uint32_t part[256];
    const int tid = threadIdx.x;
    uint32_t cnt[8];
    uint32_t lsum = 0;
#pragma unroll
    for (int j = 0; j < 8; ++j) { cnt[j] = hist1[tid * 8 + j]; lsum += cnt[j]; }
    part[tid] = lsum;
    __syncthreads();
    for (int off = 1; off < 256; off <<= 1) {   // inclusive suffix sum
        uint32_t add = (tid + off < 256) ? part[tid + off] : 0u;
        __syncthreads();
        part[tid] += add;
        __syncthreads();
    }
    const uint32_t total = part[0];
    int kk = *kptr;
    uint32_t k = (kk > 0) ? (uint32_t)kk : 0u;
    if (k == 0u) {   // keep all negatives
        if (tid == 0) { st->u_kth = 0xFFFFFFFFu; st->thr_nl = __int_as_float(0x7F800000); st->done = 1u; }
        return;
    }
    if (k > total) { // drop all negatives
        if (tid == 0) { st->u_kth = 0u; st->thr_nl = 0.0f; st->done = 1u; }
        return;
    }
    uint32_t A = (tid < 255) ? part[tid + 1] : 0u;  // strictly-above count
#pragma unroll
    for (int j = 7; j >= 0; --j) {
        uint32_t c = cnt[j];
        if (A < k && k <= A + c) {   // exactly one (thread,bin)
            st->prefix1 = (uint32_t)(tid * 8 + j);
            st->k1rem = k - A;       // done stays 0 (memset)
        }
        A += c;
    }
}

// ---------- k2_compact: keep prefix1 matches, per-wave segments, NO atomics ----------
__global__ __launch_bounds__(256) void k2_compact(
        const uint32_t* __restrict__ cand1, const uint32_t* __restrict__ wvcnt,
        uint32_t* __restrict__ cand2, uint32_t* __restrict__ wvcnt2,
        const SelState* __restrict__ st, int segw, int segw2) {
    __shared__ uint32_t s_pref, s_done;
    if (threadIdx.x == 0) { s_pref = st->prefix1; s_done = st->done; }
    __syncthreads();
    if (s_done) return;
    const uint32_t pref = s_pref;
    const int lane = threadIdx.x & 63;
    const int wid  = threadIdx.x >> 6;
    const int sidx = blockIdx.x * 4 + wid;
    const uint32_t cnt = wvcnt[sidx];
    const uint4* b4 = (const uint4*)(cand1 + (size_t)sidx * (size_t)segw);
    uint32_t* o = cand2 + (size_t)sidx * (size_t)segw2;
    uint32_t wcur = 0;
    const uint32_t iters = (cnt + 255u) >> 8;    // wave-uniform
    for (uint32_t it = 0; it < iters; ++it) {
        const uint32_t e0 = it * 256u + (uint32_t)lane * 4u;
        uint4 v = b4[it * 64u + (uint32_t)lane];   // within segw: cnt<=256*Q<=segw-4
        uint32_t u0 = (e0 + 0u < cnt && (v.x >> 21) == pref) ? v.x : 0u;
        uint32_t u1 = (e0 + 1u < cnt && (v.y >> 21) == pref) ? v.y : 0u;
        uint32_t u2 = (e0 + 2u < cnt && (v.z >> 21) == pref) ? v.z : 0u;
        uint32_t u3 = (e0 + 3u < cnt && (v.w >> 21) == pref) ? v.w : 0u;
        uint32_t m = (u0 != 0) + (u1 != 0) + (u2 != 0) + (u3 != 0);
        uint32_t excl, tot;
        wscan(m, lane, excl, tot);
        uint32_t p = wcur + excl;
        if (u0) o[p++] = u0;
        if (u1) o[p++] = u1;
        if (u2) o[p++] = u2;
        if (u3) o[p++] = u3;
        wcur += tot;
    }
    if (lane == 0) wvcnt2[sidx] = wcur;
}

// ---------- s2_final: 1 block; two LDS-histogram passes over survivors ----------
__global__ __launch_bounds__(1024) void s2_final(
        const uint32_t* __restrict__ cand2, const uint32_t* __restrict__ wvcnt2,
        SelState* __restrict__ st, int nseg, int segw2) {
    __shared__ uint32_t h[2048];
    __shared__ uint32_t cnts[4096];
    __shared__ uint32_t part[256];
    __shared__ uint32_t sel[2];
    __shared__ SelState sst;
    const int tid = threadIdx.x;
    if (tid == 0) sst = *st;
    __syncthreads();
    if (sst.done) return;
    const uint32_t prefix1 = sst.prefix1;
    const uint32_t k1 = sst.k1rem;

    for (int j = tid; j < 2048; j += 1024) h[j] = 0;
    for (int s = tid; s < nseg; s += 1024) cnts[s] = wvcnt2[s];
    __syncthreads();

    // pass 1: LDS histogram of bits [20:10] over all survivors
    for (int s = tid; s < nseg; s += 1024) {
        const uint32_t cnt = cnts[s];
        const uint32_t* base = cand2 + (size_t)s * (size_t)segw2;
        const uint4* b4 = (const uint4*)base;
        const uint32_t c4 = cnt >> 2;
        for (uint32_t j = 0; j < c4; ++j) {
            uint4 v = b4[j];
            atomicAdd(&h[(v.x >> 10) & 2047u], 1u);
            atomicAdd(&h[(v.y >> 10) & 2047u], 1u);
            atomicAdd(&h[(v.z >> 10) & 2047u], 1u);
            atomicAdd(&h[(v.w >> 10) & 2047u], 1u);
        }
        for (uint32_t j = c4 << 2; j < cnt; ++j)
            atomicAdd(&h[(base[j] >> 10) & 2047u], 1u);
    }
    __syncthreads();

    // rank-select over 2048 bins (threads 0..255, 8 bins each; suffix sums)
    uint32_t cnt8[8];
    uint32_t lsum = 0;
    if (tid < 256) {
#pragma unroll
        for (int j = 0; j < 8; ++j) { cnt8[j] = h[tid * 8 + j]; lsum += cnt8[j]; }
        part[tid] = lsum;
    }
    __syncthreads();
    for (int off = 1; off < 256; off <<= 1) {
        uint32_t add = 0;
        if (tid < 256) add = (tid + off < 256) ? part[tid + off] : 0u;
        __syncthreads();
        if (tid < 256) part[tid] += add;
        __syncthreads();
    }
    if (tid < 256) {
        uint32_t A = (tid < 255) ? part[tid + 1] : 0u;
#pragma unroll
        for (int j = 7; j >= 0; --j) {
            uint32_t c = cnt8[j];
            if (A < k1 && k1 <= A + c) { sel[0] = (uint32_t)(tid * 8 + j); sel[1] = k1 - A; }
            A += c;
        }
    }
    __syncthreads();
    const uint32_t prefix2 = sel[0];   // bits [20:10]
    const uint32_t k2 = sel[1];
    __syncthreads();

    // pass 2: LDS histogram of bits [9:0] among 22-bit-prefix matches (L2-hot)
    if (tid < 1024) h[tid] = 0;
    __syncthreads();
    for (int s = tid; s < nseg; s += 1024) {
        const uint32_t cnt = cnts[s];
        const uint32_t* base = cand2 + (size_t)s * (size_t)segw2;
        const uint4* b4 = (const uint4*)base;
        const uint32_t c4 = cnt >> 2;
        for (uint32_t j = 0; j < c4; ++j) {
            uint4 v = b4[j];
            if (((v.x >> 10) & 2047u) == prefix2) atomicAdd(&h[v.x & 1023u], 1u);
            if (((v.y >> 10) & 2047u) == prefix2) atomicAdd(&h[v.y & 1023u], 1u);
            if (((v.z >> 10) & 2047u) == prefix2) atomicAdd(&h[v.z & 1023u], 1u);
            if (((v.w >> 10) & 2047u) == prefix2) atomicAdd(&h[v.w & 1023u], 1u);
        }
        for (uint32_t j = c4 << 2; j < cnt; ++j) {
            uint32_t u = base[j];
            if (((u >> 10) & 2047u) == prefix2) atomicAdd(&h[u & 1023u], 1u);
        }
    }
    __syncthreads();

    // rank-select over 1024 bins (threads 0..255, 4 bins each)
    uint32_t cnt4[4];
    lsum = 0;
    if (tid < 256) {
#pragma unroll
        for (int j = 0; j < 4; ++j) { cnt4[j] = h[tid * 4 + j]; lsum += cnt4[j]; }
        part[tid] = lsum;
    }
    __syncthreads();
    for (int off = 1; off < 256; off <<= 1) {
        uint32_t add = 0;
        if (tid < 256) add = (tid + off < 256) ? part[tid + off] : 0u;
        __syncthreads();
        if (tid < 256) part[tid] += add;
        __syncthreads();
    }
    if (tid < 256) {
        uint32_t A = (tid < 255) ? part[tid + 1] : 0u;
#pragma unroll
        for (int j = 3; j >= 0; --j) {
            uint32_t c = cnt4[j];
            if (A < k2 && k2 <= A + c) {   // exactly one (thread,bin)
                uint32_t u = (prefix1 << 21) | (prefix2 << 10) | (uint32_t)(tid * 4 + j);
                st->u_kth = u;
                st->thr_nl = neg_loss_precise(unxform(u), -1.0f);  // t = -1 exactly
                st->done = 1u;
            }
            A += c;
        }
    }
}

// ---------------- final: fast-math values, bit-exact mask, class map ----------------
__device__ __forceinline__ float fin1c(float xx, uint32_t cls, uint32_t ukth, float thr) {
    float lp = __logf(1.0f + __expf(-fabsf(xx)));   // HW exp/log
    float v = 0.0f;
    if (cls == 1u) {                    // t = +1
        v = (fmaxf(xx, 0.0f) - xx) + lp;
    } else if (cls == 2u) {             // t = -1
        uint32_t u = xform(__float_as_uint(xx));
        bool keep = u < ukth;
        if (keep && (ukth - u) < GUARD)             // ~0 lanes hit this
            keep = neg_loss_precise(xx, -1.0f) < thr;
        if (keep) v = (fmaxf(-xx, 0.0f) + xx) + lp;
    }
    return v;
}

__device__ __forceinline__ float4 fin_quadc(float4 xv, uint32_t cb, uint32_t ukth, float thr) {
    float4 r;
    r.x = fin1c(xv.x, cb & 3u, ukth, thr);
    r.y = fin1c(xv.y, (cb >> 2) & 3u, ukth, thr);
    r.z = fin1c(xv.z, (cb >> 4) & 3u, ukth, thr);
    r.w = fin1c(xv.w, (cb >> 6) & 3u, ukth, thr);
    return r;
}

// tail helper: original t-based path
__device__ __forceinline__ float fin1t(float xx, float tt, uint32_t ukth, float thr) {
    float lp = __logf(1.0f + __expf(-fabsf(xx)));
    float v = 0.0f;
    if (tt > 0.0f) {
        v = fmaxf(xx, 0.0f) - xx * tt + lp;
    } else if (tt < 0.0f) {
        uint32_t u = xform(__float_as_uint(xx));
        bool keep = u < ukth;
        if (keep && (ukth - u) < GUARD)
            keep = neg_loss_precise(xx, tt) < thr;
        if (keep) v = fmaxf(-xx, 0.0f) - xx * tt + lp;
    }
    return v;
}

__global__ __launch_bounds__(256) void k_final(
        const float* __restrict__ x, const float* __restrict__ t,
        const uint8_t* __restrict__ cmap, const SelState* __restrict__ st,
        float* __restrict__ out, int n) {
    const uint32_t ukth = st->u_kth;
    const float thr = st->thr_nl;
    const float4* x4 = (const float4*)x;
    float4* o4 = (float4*)out;
    const int n4 = n >> 2;
    const int S = gridDim.x * 256;
    int i = blockIdx.x * 256 + threadIdx.x;
    for (; i + 3 * S < n4; i += 4 * S) {
        float4 xa = x4[i], xb = x4[i + S], xc = x4[i + 2 * S], xd = x4[i + 3 * S];
        uint32_t ca = cmap[i], cb = cmap[i + S], cc = cmap[i + 2 * S], cd = cmap[i + 3 * S];
        o4[i]         = fin_quadc(xa, ca, ukth, thr);
        o4[i + S]     = fin_quadc(xb, cb, ukth, thr);
        o4[i + 2 * S] = fin_quadc(xc, cc, ukth, thr);
        o4[i + 3 * S] = fin_quadc(xd, cd, ukth, thr);
    }
    for (; i < n4; i += S) {
        float4 xa = x4[i];
        uint32_t ca = cmap[i];
        o4[i] = fin_quadc(xa, ca, ukth, thr);
    }
    if (blockIdx.x == 0) {  // n % 4 tail: no cmap — use t directly
        for (int j = (n4 << 2) + threadIdx.x; j < n; j += 256) {
            out[j] = fin1t(x[j], t[j], ukth, thr);
        }
    }
}

extern "C" void kernel_launch(void* const* d_in, const int* in_sizes, int n_in,
                              void* d_out, int out_size, void* d_ws, size_t ws_size,
                              hipStream_t stream) {
    const float* x = (const float*)d_in[0];
    const float* t = (const float*)d_in[1];
    const int* kptr = (const int*)d_in[2];
    float* out = (float*)d_out;
    const int n = in_sizes[0];
    if (n <= 0) return;

    const int n4 = n >> 2;
    int work = (n4 + 255) / 256;
    if (work < 1) work = 1;
    int grid = work < 1024 ? work : 1024;   // 4 blocks/CU
    const int S = grid * 256;
    const int Q = (n4 + S - 1) / S;          // max quads per thread
    const int segw = 256 * Q + 4;            // words per wave segment (16B-aligned)
    const int nseg = grid * 4;               // <= 4096

    char* ws = (char*)d_ws;
    uint32_t* hist1 = (uint32_t*)(ws + 0);          // 2048 u32
    SelState* st    = (SelState*)(ws + 20480);
    uint32_t* wvcnt = (uint32_t*)(ws + 24576);      // nseg u32 (always written)
    uint8_t*  cmap  = (uint8_t*)(ws + 40960);       // n4 bytes
    size_t c1off = (40960 + (size_t)n4 + 255) & ~(size_t)255;
    uint32_t* cand1 = (uint32_t*)(ws + c1off);      // nseg*segw u32 (~42 MB)
    size_t c2off = (c1off + (size_t)nseg * (size_t)segw * 4u + 255) & ~(size_t)255;
    uint32_t* cand2 = (uint32_t*)(ws + c2off);      // nseg*segw u32 (~42 MB)
    size_t w2off = (c2off + (size_t)nseg * (size_t)segw * 4u + 255) & ~(size_t)255;
    uint32_t* wvcnt2 = (uint32_t*)(ws + w2off);     // nseg u32 (always written)

    // zero hist1 + state only (~20 KB)
    hipMemsetAsync(d_ws, 0, 20544, stream);

    k1_hist   <<<grid, 256, 0, stream>>>(x, t, hist1, cand1, wvcnt, cmap, n, segw);
    s1_scan   <<<1, 256, 0, stream>>>(hist1, st, kptr);
    k2_compact<<<grid, 256, 0, stream>>>(cand1, wvcnt, cand2, wvcnt2, st, segw, segw);
    s2_final  <<<1, 1024, 0, stream>>>(cand2, wvcnt2, st, nseg, segw);
    k_final   <<<grid, 256, 0, stream>>>(x, t, cmap, st, out, n);
}

// Round 3
// 192.679 us; speedup vs baseline: 1.2082x; 1.2082x over previous
//
#include <hip/hip_runtime.h>
#include <cstdint>
#include <cstddef>

// Exact radix select on order-transformed x bits among t<0 entries
// (t = -1 exactly => negative_loss = softplus(x), strictly increasing in x).
//
// R7 structure (fixes R6's 76 µs latency-bound single-block s2_final):
//   k1:        82 MB read; 2048-bin LDS hist (bits[31:21]); compacts ALL
//              negatives' u into per-wave cand1 segments (13.7 MB, no atomics);
//              emits 2-bit class map (2.56 MB) for k_final.
//   s1:        1 block — pick 11-bit prefix1 + rank k1rem.
//   k2_compact:reads cand1 (13.7 MB), keeps prefix1 matches (~100-300k)
//              into per-wave cand2 segments + wvcnt2. Zero global atomics.
//   s2a_scan:  1 block — exclusive prefix sum of wvcnt2[nseg] -> offs, total.
//   k2b_gather:wave-per-segment copy cand2 -> contiguous cand3 (scan-placed,
//              atomic-free; parallel across 4096 waves).
//   s2_final:  1 block, 1024 thr — two LDS-histogram passes over CONTIGUOUS
//              cand3 (coalesced uint4, stride-1024: full MLP; R6's version
//              walked 4096 scattered segments serially per thread = pure
//              latency chain at 7 GB/s). bits[20:10] then bits[9:0]
//              -> exact u_kth + precise loss threshold.
//   k_final:   x + cmap read (no t re-read), fast __expf/__logf values,
//              bit-exact mask, precise re-check only in 256-ulp guard band.
//
// Atomic-design ledger (measured):
//   R5: 75k device atomics on 4 KB hist   -> 64-line ping-pong, 47 µs. BAD.
//   R6: single block over scattered segs  -> latency chain, 76 µs. BAD.
//   R7: scan-based placement, zero global atomics on hot lines; single
//       select block only ever reads contiguous memory. LDS atomics only.

struct SelState {
    uint32_t prefix1;  // 11-bit level-1 prefix (bits 31:21)
    uint32_t k1rem;    // remaining rank within level-1 bin (1-based)
    uint32_t prefix2;  // unused (layout stability)
    uint32_t k2rem;    // unused
    uint32_t u_kth;    // final: transformed bits of k-th largest x
    float    thr_nl;   // final: precise loss-space threshold
    uint32_t done;
};

#define GUARD 256u

__device__ __forceinline__ uint32_t xform(uint32_t b) {
    return ((int32_t)b < 0) ? ~b : (b | 0x80000000u);
}
__device__ __forceinline__ float unxform(uint32_t u) {
    uint32_t b = (u & 0x80000000u) ? (u ^ 0x80000000u) : ~u;
    return __uint_as_float(b);
}
// precise chain — matches reference fp32 semantics; used only for the
// threshold value and the rare guard-band compare.
__device__ __forceinline__ float neg_loss_precise(float x, float t) {
#pragma clang fp contract(off)
    return (fmaxf(-x, 0.0f) - x * t) + log1pf(expf(-fabsf(x)));
}

// wave-wide inclusive scan -> exclusive offset + total (64 lanes)
__device__ __forceinline__ void wscan(uint32_t m, int lane, uint32_t& excl, uint32_t& tot) {
    uint32_t inc = m;
#pragma unroll
    for (int d = 1; d < 64; d <<= 1) {
        uint32_t v = __shfl_up(inc, (unsigned)d, 64);
        if (lane >= d) inc += v;
    }
    excl = inc - m;
    tot = __shfl(inc, 63, 64);
}

// per-quad: u values (0 if not negative), class byte, LDS histogram
__device__ __forceinline__ uint32_t quad_u_cls(uint32_t* my, float4 xv, float4 tv,
        uint32_t& u0, uint32_t& u1, uint32_t& u2, uint32_t& u3) {
    u0 = (tv.x < 0.0f) ? xform(__float_as_uint(xv.x)) : 0u;
    u1 = (tv.y < 0.0f) ? xform(__float_as_uint(xv.y)) : 0u;
    u2 = (tv.z < 0.0f) ? xform(__float_as_uint(xv.z)) : 0u;
    u3 = (tv.w < 0.0f) ? xform(__float_as_uint(xv.w)) : 0u;
    uint32_t cls = ((tv.x > 0.0f) ? 1u : ((tv.x < 0.0f) ? 2u : 0u))
                 | (((tv.y > 0.0f) ? 1u : ((tv.y < 0.0f) ? 2u : 0u)) << 2)
                 | (((tv.z > 0.0f) ? 1u : ((tv.z < 0.0f) ? 2u : 0u)) << 4)
                 | (((tv.w > 0.0f) ? 1u : ((tv.w < 0.0f) ? 2u : 0u)) << 6);
    if (u0) atomicAdd(&my[u0 >> 21], 1u);
    if (u1) atomicAdd(&my[u1 >> 21], 1u);
    if (u2) atomicAdd(&my[u2 >> 21], 1u);
    if (u3) atomicAdd(&my[u3 >> 21], 1u);
    return cls;
}

// ---------- k1: 11-bit LDS histogram + negative compaction + class map ----------
__global__ __launch_bounds__(256) void k1_hist(
        const float* __restrict__ x, const float* __restrict__ t,
        uint32_t* __restrict__ hist1, uint32_t* __restrict__ cand1,
        uint32_t* __restrict__ wvcnt, uint8_t* __restrict__ cmap,
        int n, int segw) {
    __shared__ uint32_t lh[2 * 2049];   // 2-way replicated (+1 pad)
    for (int j = threadIdx.x; j < 2 * 2049; j += 256) lh[j] = 0;
    __syncthreads();
    uint32_t* my = &lh[(threadIdx.x & 1) * 2049];

    const float4* x4 = (const float4*)x;
    const float4* t4 = (const float4*)t;
    const int n4 = n >> 2;
    const int S = gridDim.x * 256;
    const int lane = threadIdx.x & 63;
    const int wid  = threadIdx.x >> 6;
    uint32_t* wseg = cand1 + (size_t)(blockIdx.x * 4 + wid) * (size_t)segw;
    uint32_t wcur = 0;   // wave-uniform segment cursor (no atomics)

    // block-uniform count of full 4x-unrolled batches (appends use wave-wide
    // shfl scans, so the unrolled loop must be wave-uniform)
    int M4 = 0;
    {
        long rem = (long)n4 - 1 - (long)(blockIdx.x * 256 + 255);
        if (rem >= 0) {
            long T = rem / S;
            if (T >= 3) M4 = (int)((T - 3) / 4 + 1);
        }
    }
    int i = blockIdx.x * 256 + threadIdx.x;

    for (int b = 0; b < M4; ++b, i += 4 * S) {   // 8 independent 16B loads in flight
        float4 xa = x4[i], xb = x4[i + S], xc = x4[i + 2 * S], xd = x4[i + 3 * S];
        float4 ta = t4[i], tb = t4[i + S], tc = t4[i + 2 * S], td = t4[i + 3 * S];
        uint32_t u0, u1, u2, u3, u4_, u5, u6, u7, u8, u9, uA, uB, uC, uD, uE, uF;
        uint32_t ca = quad_u_cls(my, xa, ta, u0, u1, u2, u3);
        uint32_t cb = quad_u_cls(my, xb, tb, u4_, u5, u6, u7);
        uint32_t cc = quad_u_cls(my, xc, tc, u8, u9, uA, uB);
        uint32_t cd = quad_u_cls(my, xd, td, uC, uD, uE, uF);
        cmap[i]         = (uint8_t)ca;
        cmap[i + S]     = (uint8_t)cb;
        cmap[i + 2 * S] = (uint8_t)cc;
        cmap[i + 3 * S] = (uint8_t)cd;
        uint32_t m = (u0 != 0) + (u1 != 0) + (u2 != 0) + (u3 != 0)
                   + (u4_ != 0) + (u5 != 0) + (u6 != 0) + (u7 != 0)
                   + (u8 != 0) + (u9 != 0) + (uA != 0) + (uB != 0)
                   + (uC != 0) + (uD != 0) + (uE != 0) + (uF != 0);
        uint32_t excl, tot;
        wscan(m, lane, excl, tot);
        uint32_t p = wcur + excl;
        if (u0)  wseg[p++] = u0;
        if (u1)  wseg[p++] = u1;
        if (u2)  wseg[p++] = u2;
        if (u3)  wseg[p++] = u3;
        if (u4_) wseg[p++] = u4_;
        if (u5)  wseg[p++] = u5;
        if (u6)  wseg[p++] = u6;
        if (u7)  wseg[p++] = u7;
        if (u8)  wseg[p++] = u8;
        if (u9)  wseg[p++] = u9;
        if (uA)  wseg[p++] = uA;
        if (uB)  wseg[p++] = uB;
        if (uC)  wseg[p++] = uC;
        if (uD)  wseg[p++] = uD;
        if (uE)  wseg[p++] = uE;
        if (uF)  wseg[p++] = uF;
        wcur += tot;
    }

    // masked single-quad remainder (wave-uniform loop via __any)
    for (; __any(i < n4); i += S) {
        const bool act = i < n4;
        float4 xa = act ? x4[i] : make_float4(0.f, 0.f, 0.f, 0.f);
        float4 ta = act ? t4[i] : make_float4(0.f, 0.f, 0.f, 0.f);
        uint32_t u0, u1, u2, u3;
        uint32_t ca = quad_u_cls(my, xa, ta, u0, u1, u2, u3);
        if (act) cmap[i] = (uint8_t)ca;
        uint32_t m = (u0 != 0) + (u1 != 0) + (u2 != 0) + (u3 != 0);
        uint32_t excl, tot;
        wscan(m, lane, excl, tot);
        uint32_t p = wcur + excl;
        if (u0) wseg[p++] = u0;
        if (u1) wseg[p++] = u1;
        if (u2) wseg[p++] = u2;
        if (u3) wseg[p++] = u3;
        wcur += tot;
    }

    // n % 4 tail (block 0 only; <4 elems; no cmap — k_final reads t for tail)
    if (blockIdx.x == 0) {
        int j = (n4 << 2) + threadIdx.x;
        const bool act = j < n;
        float xx = act ? x[j] : 0.0f;
        float tt = act ? t[j] : 0.0f;
        uint32_t u0 = (tt < 0.0f) ? xform(__float_as_uint(xx)) : 0u;
        if (u0) atomicAdd(&my[u0 >> 21], 1u);
        uint32_t excl, tot;
        wscan(u0 != 0 ? 1u : 0u, lane, excl, tot);
        if (u0) wseg[wcur + excl] = u0;
        wcur += tot;
    }

    if (lane == 0) wvcnt[blockIdx.x * 4 + wid] = wcur;

    __syncthreads();
    for (int b2 = threadIdx.x; b2 < 2048; b2 += 256) {
        uint32_t c = lh[b2] + lh[2049 + b2];
        if (c) atomicAdd(&hist1[b2], c);
    }
}

// ---------------- s1: 1 block, pick 11-bit prefix ----------------
__global__ __launch_bounds__(256) void s1_scan(
        const uint32_t* __restrict__ hist1, SelState* __restrict__ st,
        const int* __restrict__ kptr) {
    __shared__ uint32_t part[256];
    const int tid = threadIdx.x;
    uint32_t cnt[8];
    uint32_t lsum = 0;
#pragma unroll
    for (int j = 0; j < 8; ++j) { cnt[j] = hist1[tid * 8 + j]; lsum += cnt[j]; }
    part[tid] = lsum;
    __syncthreads();
    for (int off = 1; off < 256; off <<= 1) {   // inclusive suffix sum
        uint32_t add = (tid + off < 256) ? part[tid + off] : 0u;
        __syncthreads();
        part[tid] += add;
        __syncthreads();
    }
    const uint32_t total = part[0];
    int kk = *kptr;
    uint32_t k = (kk > 0) ? (uint32_t)kk : 0u;
    if (k == 0u) {   // keep all negatives
        if (tid == 0) { st->u_kth = 0xFFFFFFFFu; st->thr_nl = __int_as_float(0x7F800000); st->done = 1u; }
        return;
    }
    if (k > total) { // drop all negatives
        if (tid == 0) { st->u_kth = 0u; st->thr_nl = 0.0f; st->done = 1u; }
        return;
    }
    uint32_t A = (tid < 255) ? part[tid + 1] : 0u;  // strictly-above count
#pragma unroll
    for (int j = 7; j >= 0; --j) {
        uint32_t c = cnt[j];
        if (A < k && k <= A + c) {   // exactly one (thread,bin)
            st->prefix1 = (uint32_t)(tid * 8 + j);
            st->k1rem = k - A;       // done stays 0 (memset)
        }
        A += c;
    }
}

// ---------- k2_compact: keep prefix1 matches, per-wave segments, NO atomics ----------
__global__ __launch_bounds__(256) void k2_compact(
        const uint32_t* __restrict__ cand1, const uint32_t* __restrict__ wvcnt,
        uint32_t* __restrict__ cand2, uint32_t* __restrict__ wvcnt2,
        const SelState* __restrict__ st, int segw) {
    __shared__ uint32_t s_pref, s_done;
    if (threadIdx.x == 0) { s_pref = st->prefix1; s_done = st->done; }
    __syncthreads();
    if (s_done) return;
    const uint32_t pref = s_pref;
    const int lane = threadIdx.x & 63;
    const int wid  = threadIdx.x >> 6;
    const int sidx = blockIdx.x * 4 + wid;
    const uint32_t cnt = wvcnt[sidx];
    const uint4* b4 = (const uint4*)(cand1 + (size_t)sidx * (size_t)segw);
    uint32_t* o = cand2 + (size_t)sidx * (size_t)segw;
    uint32_t wcur = 0;
    const uint32_t iters = (cnt + 255u) >> 8;    // wave-uniform
    for (uint32_t it = 0; it < iters; ++it) {
        const uint32_t e0 = it * 256u + (uint32_t)lane * 4u;
        uint4 v = b4[it * 64u + (uint32_t)lane];   // within segw: cnt<=256*Q<=segw-4
        uint32_t u0 = (e0 + 0u < cnt && (v.x >> 21) == pref) ? v.x : 0u;
        uint32_t u1 = (e0 + 1u < cnt && (v.y >> 21) == pref) ? v.y : 0u;
        uint32_t u2 = (e0 + 2u < cnt && (v.z >> 21) == pref) ? v.z : 0u;
        uint32_t u3 = (e0 + 3u < cnt && (v.w >> 21) == pref) ? v.w : 0u;
        uint32_t m = (u0 != 0) + (u1 != 0) + (u2 != 0) + (u3 != 0);
        uint32_t excl, tot;
        wscan(m, lane, excl, tot);
        uint32_t p = wcur + excl;
        if (u0) o[p++] = u0;
        if (u1) o[p++] = u1;
        if (u2) o[p++] = u2;
        if (u3) o[p++] = u3;
        wcur += tot;
    }
    if (lane == 0) wvcnt2[sidx] = wcur;
}

// ---------- s2a: 1 block — exclusive prefix sum of wvcnt2 -> offs, total ----------
__global__ __launch_bounds__(256) void s2a_scan(
        const uint32_t* __restrict__ wvcnt2, uint32_t* __restrict__ offs,
        uint32_t* __restrict__ total2, const SelState* __restrict__ st, int nseg) {
    __shared__ uint32_t part[256];
    __shared__ uint32_t s_done;
    const int tid = threadIdx.x;
    if (tid == 0) s_done = st->done;
    __syncthreads();
    if (s_done) return;
    // 16 counts per thread via 4 uint4 loads (region reserved 16 KB; masked)
    uint32_t v[16];
    const uint4* w4 = (const uint4*)wvcnt2;
    uint32_t lsum = 0;
#pragma unroll
    for (int q = 0; q < 4; ++q) {
        uint4 a = w4[tid * 4 + q];
        int base = tid * 16 + q * 4;
        v[q * 4 + 0] = (base + 0 < nseg) ? a.x : 0u;
        v[q * 4 + 1] = (base + 1 < nseg) ? a.y : 0u;
        v[q * 4 + 2] = (base + 2 < nseg) ? a.z : 0u;
        v[q * 4 + 3] = (base + 3 < nseg) ? a.w : 0u;
        lsum += v[q * 4 + 0] + v[q * 4 + 1] + v[q * 4 + 2] + v[q * 4 + 3];
    }
    part[tid] = lsum;
    __syncthreads();
    for (int off = 1; off < 256; off <<= 1) {   // inclusive forward scan
        uint32_t add = (tid >= off) ? part[tid - off] : 0u;
        __syncthreads();
        part[tid] += add;
        __syncthreads();
    }
    uint32_t base = part[tid] - lsum;           // exclusive
#pragma unroll
    for (int j = 0; j < 16; ++j) {
        int idx = tid * 16 + j;
        if (idx < nseg) offs[idx] = base;
        base += v[j];
    }
    if (tid == 255) *total2 = part[255];
}

// ---------- k2b: wave-per-segment gather to contiguous cand3 ----------
__global__ __launch_bounds__(256) void k2b_gather(
        const uint32_t* __restrict__ cand2, const uint32_t* __restrict__ wvcnt2,
        const uint32_t* __restrict__ offs, uint32_t* __restrict__ cand3,
        const SelState* __restrict__ st, int segw) {
    __shared__ uint32_t s_done;
    if (threadIdx.x == 0) s_done = st->done;
    __syncthreads();
    if (s_done) return;
    const int lane = threadIdx.x & 63;
    const int wid  = threadIdx.x >> 6;
    const int sidx = blockIdx.x * 4 + wid;
    const uint32_t cnt = wvcnt2[sidx];
    const uint32_t off = offs[sidx];
    const uint32_t* src = cand2 + (size_t)sidx * (size_t)segw;
    for (uint32_t j = lane; j < cnt; j += 64) cand3[off + j] = src[j];
}

// ---------- s2_final: 1 block; two LDS-hist passes over CONTIGUOUS cand3 ----------
__global__ __launch_bounds__(1024) void s2_final(
        const uint32_t* __restrict__ cand3, const uint32_t* __restrict__ total2,
        SelState* __restrict__ st) {
    __shared__ uint32_t h[2 * 2049];   // 2-way replicated (+1 pad)
    __shared__ uint32_t part[256];
    __shared__ uint32_t sel[2];
    __shared__ SelState sst;
    __shared__ uint32_t s_tot;
    const int tid = threadIdx.x;
    if (tid == 0) { sst = *st; s_tot = *total2; }
    __syncthreads();
    if (sst.done) return;
    const uint32_t prefix1 = sst.prefix1;
    const uint32_t k1 = sst.k1rem;
    const uint32_t total = s_tot;
    uint32_t* my = &h[(tid & 1) * 2049];

    for (int j = tid; j < 2 * 2049; j += 1024) h[j] = 0;
    __syncthreads();

    // pass 1: LDS histogram of bits [20:10]; coalesced uint4, stride-1024
    const uint4* b4 = (const uint4*)cand3;
    const uint32_t c4 = total >> 2;
    for (uint32_t j = tid; j < c4; j += 1024) {
        uint4 v = b4[j];
        atomicAdd(&my[(v.x >> 10) & 2047u], 1u);
        atomicAdd(&my[(v.y >> 10) & 2047u], 1u);
        atomicAdd(&my[(v.z >> 10) & 2047u], 1u);
        atomicAdd(&my[(v.w >> 10) & 2047u], 1u);
    }
    if (tid < (int)(total & 3u)) {
        uint32_t u = cand3[(c4 << 2) + tid];
        atomicAdd(&my[(u >> 10) & 2047u], 1u);
    }
    __syncthreads();

    // rank-select over 2048 bins (threads 0..255, 8 bins each; suffix sums)
    uint32_t cnt8[8];
    uint32_t lsum = 0;
    if (tid < 256) {
#pragma unroll
        for (int j = 0; j < 8; ++j) {
            int b = tid * 8 + j;
            cnt8[j] = h[b] + h[2049 + b];
            lsum += cnt8[j];
        }
        part[tid] = lsum;
    }
    __syncthreads();
    for (int off = 1; off < 256; off <<= 1) {
        uint32_t add = 0;
        if (tid < 256) add = (tid + off < 256) ? part[tid + off] : 0u;
        __syncthreads();
        if (tid < 256) part[tid] += add;
        __syncthreads();
    }
    if (tid < 256) {
        uint32_t A = (tid < 255) ? part[tid + 1] : 0u;
#pragma unroll
        for (int j = 7; j >= 0; --j) {
            uint32_t c = cnt8[j];
            if (A < k1 && k1 <= A + c) { sel[0] = (uint32_t)(tid * 8 + j); sel[1] = k1 - A; }
            A += c;
        }
    }
    __syncthreads();
    const uint32_t prefix2 = sel[0];   // bits [20:10]
    const uint32_t k2 = sel[1];
    __syncthreads();

    // pass 2: LDS histogram of bits [9:0] among 22-bit-prefix matches (L2-hot)
    for (int j = tid; j < 2 * 2049; j += 1024) h[j] = 0;
    __syncthreads();
    for (uint32_t j = tid; j < c4; j += 1024) {
        uint4 v = b4[j];
        if (((v.x >> 10) & 2047u) == prefix2) atomicAdd(&my[v.x & 1023u], 1u);
        if (((v.y >> 10) & 2047u) == prefix2) atomicAdd(&my[v.y & 1023u], 1u);
        if (((v.z >> 10) & 2047u) == prefix2) atomicAdd(&my[v.z & 1023u], 1u);
        if (((v.w >> 10) & 2047u) == prefix2) atomicAdd(&my[v.w & 1023u], 1u);
    }
    if (tid < (int)(total & 3u)) {
        uint32_t u = cand3[(c4 << 2) + tid];
        if (((u >> 10) & 2047u) == prefix2) atomicAdd(&my[u & 1023u], 1u);
    }
    __syncthreads();

    // rank-select over 1024 bins (threads 0..255, 4 bins each)
    uint32_t cnt4[4];
    lsum = 0;
    if (tid < 256) {
#pragma unroll
        for (int j = 0; j < 4; ++j) {
            int b = tid * 4 + j;
            cnt4[j] = h[b] + h[2049 + b];
            lsum += cnt4[j];
        }
        part[tid] = lsum;
    }
    __syncthreads();
    for (int off = 1; off < 256; off <<= 1) {
        uint32_t add = 0;
        if (tid < 256) add = (tid + off < 256) ? part[tid + off] : 0u;
        __syncthreads();
        if (tid < 256) part[tid] += add;
        __syncthreads();
    }
    if (tid < 256) {
        uint32_t A = (tid < 255) ? part[tid + 1] : 0u;
#pragma unroll
        for (int j = 3; j >= 0; --j) {
            uint32_t c = cnt4[j];
            if (A < k2 && k2 <= A + c) {   // exactly one (thread,bin)
                uint32_t u = (prefix1 << 21) | (prefix2 << 10) | (uint32_t)(tid * 4 + j);
                st->u_kth = u;
                st->thr_nl = neg_loss_precise(unxform(u), -1.0f);  // t = -1 exactly
                st->done = 1u;
            }
            A += c;
        }
    }
}

// ---------------- final: fast-math values, bit-exact mask, class map ----------------
__device__ __forceinline__ float fin1c(float xx, uint32_t cls, uint32_t ukth, float thr) {
    float lp = __logf(1.0f + __expf(-fabsf(xx)));   // HW exp/log
    float v = 0.0f;
    if (cls == 1u) {                    // t = +1
        v = (fmaxf(xx, 0.0f) - xx) + lp;
    } else if (cls == 2u) {             // t = -1
        uint32_t u = xform(__float_as_uint(xx));
        bool keep = u < ukth;
        if (keep && (ukth - u) < GUARD)             // ~0 lanes hit this
            keep = neg_loss_precise(xx, -1.0f) < thr;
        if (keep) v = (fmaxf(-xx, 0.0f) + xx) + lp;
    }
    return v;
}

__device__ __forceinline__ float4 fin_quadc(float4 xv, uint32_t cb, uint32_t ukth, float thr) {
    float4 r;
    r.x = fin1c(xv.x, cb & 3u, ukth, thr);
    r.y = fin1c(xv.y, (cb >> 2) & 3u, ukth, thr);
    r.z = fin1c(xv.z, (cb >> 4) & 3u, ukth, thr);
    r.w = fin1c(xv.w, (cb >> 6) & 3u, ukth, thr);
    return r;
}

// tail helper: original t-based path
__device__ __forceinline__ float fin1t(float xx, float tt, uint32_t ukth, float thr) {
    float lp = __logf(1.0f + __expf(-fabsf(xx)));
    float v = 0.0f;
    if (tt > 0.0f) {
        v = fmaxf(xx, 0.0f) - xx * tt + lp;
    } else if (tt < 0.0f) {
        uint32_t u = xform(__float_as_uint(xx));
        bool keep = u < ukth;
        if (keep && (ukth - u) < GUARD)
            keep = neg_loss_precise(xx, tt) < thr;
        if (keep) v = fmaxf(-xx, 0.0f) - xx * tt + lp;
    }
    return v;
}

__global__ __launch_bounds__(256) void k_final(
        const float* __restrict__ x, const float* __restrict__ t,
        const uint8_t* __restrict__ cmap, const SelState* __restrict__ st,
        float* __restrict__ out, int n) {
    const uint32_t ukth = st->u_kth;
    const float thr = st->thr_nl;
    const float4* x4 = (const float4*)x;
    float4* o4 = (float4*)out;
    const int n4 = n >> 2;
    const int S = gridDim.x * 256;
    int i = blockIdx.x * 256 + threadIdx.x;
    for (; i + 3 * S < n4; i += 4 * S) {
        float4 xa = x4[i], xb = x4[i + S], xc = x4[i + 2 * S], xd = x4[i + 3 * S];
        uint32_t ca = cmap[i], cb = cmap[i + S], cc = cmap[i + 2 * S], cd = cmap[i + 3 * S];
        o4[i]         = fin_quadc(xa, ca, ukth, thr);
        o4[i + S]     = fin_quadc(xb, cb, ukth, thr);
        o4[i + 2 * S] = fin_quadc(xc, cc, ukth, thr);
        o4[i + 3 * S] = fin_quadc(xd, cd, ukth, thr);
    }
    for (; i < n4; i += S) {
        float4 xa = x4[i];
        uint32_t ca = cmap[i];
        o4[i] = fin_quadc(xa, ca, ukth, thr);
    }
    if (blockIdx.x == 0) {  // n % 4 tail: no cmap — use t directly
        for (int j = (n4 << 2) + threadIdx.x; j < n; j += 256) {
            out[j] = fin1t(x[j], t[j], ukth, thr);
        }
    }
}

extern "C" void kernel_launch(void* const* d_in, const int* in_sizes, int n_in,
                              void* d_out, int out_size, void* d_ws, size_t ws_size,
                              hipStream_t stream) {
    const float* x = (const float*)d_in[0];
    const float* t = (const float*)d_in[1];
    const int* kptr = (const int*)d_in[2];
    float* out = (float*)d_out;
    const int n = in_sizes[0];
    if (n <= 0) return;

    const int n4 = n >> 2;
    int work = (n4 + 255) / 256;
    if (work < 1) work = 1;
    int grid = work < 1024 ? work : 1024;   // 4 blocks/CU
    const int S = grid * 256;
    const int Q = (n4 + S - 1) / S;          // max quads per thread
    const int segw = 256 * Q + 4;            // words per wave segment (16B-aligned)
    const int nseg = grid * 4;               // <= 4096

    char* ws = (char*)d_ws;
    uint32_t* hist1  = (uint32_t*)(ws + 0);          // 2048 u32
    SelState* st     = (SelState*)(ws + 20480);
    uint32_t* total2 = (uint32_t*)(ws + 20544);
    uint32_t* wvcnt  = (uint32_t*)(ws + 24576);      // 16 KB reserved
    uint8_t*  cmap   = (uint8_t*)(ws + 40960);       // n4 bytes
    size_t c1off = (40960 + (size_t)n4 + 255) & ~(size_t)255;
    uint32_t* cand1  = (uint32_t*)(ws + c1off);      // nseg*segw u32 (~42 MB)
    size_t c2off = (c1off + (size_t)nseg * (size_t)segw * 4u + 255) & ~(size_t)255;
    uint32_t* cand2  = (uint32_t*)(ws + c2off);      // nseg*segw u32 (~42 MB)
    size_t w2off = (c2off + (size_t)nseg * (size_t)segw * 4u + 255) & ~(size_t)255;
    uint32_t* wvcnt2 = (uint32_t*)(ws + w2off);      // 16 KB reserved
    uint32_t* offs   = (uint32_t*)(ws + w2off + 16384);   // 16 KB reserved
    size_t c3off = w2off + 32768;
    uint32_t* cand3  = (uint32_t*)(ws + c3off);      // worst-case nseg*segw u32

    // zero hist1 + state + total only (~20 KB)
    hipMemsetAsync(d_ws, 0, 20608, stream);

    k1_hist   <<<grid, 256, 0, stream>>>(x, t, hist1, cand1, wvcnt, cmap, n, segw);
    s1_scan   <<<1, 256, 0, stream>>>(hist1, st, kptr);
    k2_compact<<<grid, 256, 0, stream>>>(cand1, wvcnt, cand2, wvcnt2, st, segw);
    s2a_scan  <<<1, 256, 0, stream>>>(wvcnt2, offs, total2, st, nseg);
    k2b_gather<<<grid, 256, 0, stream>>>(cand2, wvcnt2, offs, cand3, st, segw);
    s2_final  <<<1, 1024, 0, stream>>>(cand3, total2, st);
    k_final   <<<grid, 256, 0, stream>>>(x, t, cmap, st, out, n);
}

// Round 4
// 167.068 us; speedup vs baseline: 1.3934x; 1.1533x over previous
//
#include <hip/hip_runtime.h>
#include <cstdint>
#include <cstddef>

// Exact radix select on order-transformed x bits among t<0 entries
// (t = -1 exactly => negative_loss = softplus(x), strictly increasing in x).
//
// R8 structure (convergence of measured-good pieces):
//   k1:        82 MB read; 2048-bin LDS hist (bits[31:21]) merged into an
//              8-way REPLICATED global hist (R0..R7 merged 2M atomics onto a
//              single 8 KB/128-line hist = R5-style line ping-pong; replicas
//              spread it 8x); compacts negatives' u into per-wave cand1
//              segments (13.7 MB, no atomics); emits 2-bit class map.
//   s1:        1 block — sum 8 replicas, pick 11-bit prefix1 + rank k1rem.
//   k2_sel21:  wave-per-own-segment read of cand1 (~13.7 MB, L2/L3-hot,
//              same-block locality), filter prefix1 (~140k survivors),
//              scatter-atomic into 2^21-bin hist21 (bits[20:0], 8 MB).
//              Scattered lines -> no ping-pong (proven in the 177 µs R0).
//   scan2a:    1024 blocks — per-chunk sums of hist21 (8 MB parallel read).
//   scan2b:    1 block — pick chunk then bin -> exact u_kth + precise thr.
//   k_final:   x + cmap read (no t re-read), fast __expf/__logf values,
//              bit-exact mask, precise re-check only in 256-ulp guard band.
//
// Atomic-design ledger (measured):
//   R5: 140k device atomics on 4 KB hist  -> 64-line ping-pong, 47 us. BAD.
//   R6: single block over scattered segs  -> latency chain, 76 us. BAD.
//   R7: single block streaming 2x ~1 MB   -> single-CU BW bound, slow. MEH.
//   R8: scattered 2^21-bin device scatter (proven R0) + replicated hist1
//       merge + all mid-chain kernels grid-parallel except tiny scans.
//
// ws layout:
//   [0      ..  65536)  hrep    (8 x 2048 u32 replicated hist1)
//   [65536  ..  65600)  SelState
//   [65792  .. +8 MB)   hist21  (2^21 u32, bits [20:0])
//   [~8.45M .. +4 KB)   csums   (1024 u32 chunk sums)
//   [.. +16 KB)         wvcnt   (<=4096 u32, always written)
//   [..  +n/4)          cmap    (class byte per quad)
//   [align256 ..)       cand1   (nseg * segw u32)

struct SelState {
    uint32_t prefix1;  // 11-bit level-1 prefix (bits 31:21)
    uint32_t k1rem;    // remaining rank within level-1 bin (1-based)
    uint32_t prefix2;  // unused (layout stability)
    uint32_t k2rem;    // unused
    uint32_t u_kth;    // final: transformed bits of k-th largest x
    float    thr_nl;   // final: precise loss-space threshold
    uint32_t done;
};

#define GUARD 256u
#define HREP 8

__device__ __forceinline__ uint32_t xform(uint32_t b) {
    return ((int32_t)b < 0) ? ~b : (b | 0x80000000u);
}
__device__ __forceinline__ float unxform(uint32_t u) {
    uint32_t b = (u & 0x80000000u) ? (u ^ 0x80000000u) : ~u;
    return __uint_as_float(b);
}
// precise chain — matches reference fp32 semantics; used only for the
// threshold value and the rare guard-band compare.
__device__ __forceinline__ float neg_loss_precise(float x, float t) {
#pragma clang fp contract(off)
    return (fmaxf(-x, 0.0f) - x * t) + log1pf(expf(-fabsf(x)));
}

// wave-wide inclusive scan -> exclusive offset + total (64 lanes)
__device__ __forceinline__ void wscan(uint32_t m, int lane, uint32_t& excl, uint32_t& tot) {
    uint32_t inc = m;
#pragma unroll
    for (int d = 1; d < 64; d <<= 1) {
        uint32_t v = __shfl_up(inc, (unsigned)d, 64);
        if (lane >= d) inc += v;
    }
    excl = inc - m;
    tot = __shfl(inc, 63, 64);
}

// per-quad: u values (0 if not negative), class byte, LDS histogram
__device__ __forceinline__ uint32_t quad_u_cls(uint32_t* my, float4 xv, float4 tv,
        uint32_t& u0, uint32_t& u1, uint32_t& u2, uint32_t& u3) {
    u0 = (tv.x < 0.0f) ? xform(__float_as_uint(xv.x)) : 0u;
    u1 = (tv.y < 0.0f) ? xform(__float_as_uint(xv.y)) : 0u;
    u2 = (tv.z < 0.0f) ? xform(__float_as_uint(xv.z)) : 0u;
    u3 = (tv.w < 0.0f) ? xform(__float_as_uint(xv.w)) : 0u;
    uint32_t cls = ((tv.x > 0.0f) ? 1u : ((tv.x < 0.0f) ? 2u : 0u))
                 | (((tv.y > 0.0f) ? 1u : ((tv.y < 0.0f) ? 2u : 0u)) << 2)
                 | (((tv.z > 0.0f) ? 1u : ((tv.z < 0.0f) ? 2u : 0u)) << 4)
                 | (((tv.w > 0.0f) ? 1u : ((tv.w < 0.0f) ? 2u : 0u)) << 6);
    if (u0) atomicAdd(&my[u0 >> 21], 1u);
    if (u1) atomicAdd(&my[u1 >> 21], 1u);
    if (u2) atomicAdd(&my[u2 >> 21], 1u);
    if (u3) atomicAdd(&my[u3 >> 21], 1u);
    return cls;
}

// ---------- k1: 11-bit LDS histogram + negative compaction + class map ----------
__global__ __launch_bounds__(256) void k1_hist(
        const float* __restrict__ x, const float* __restrict__ t,
        uint32_t* __restrict__ hrep, uint32_t* __restrict__ cand1,
        uint32_t* __restrict__ wvcnt, uint8_t* __restrict__ cmap,
        int n, int segw) {
    __shared__ uint32_t lh[2 * 2049];   // 2-way replicated (+1 pad)
    for (int j = threadIdx.x; j < 2 * 2049; j += 256) lh[j] = 0;
    __syncthreads();
    uint32_t* my = &lh[(threadIdx.x & 1) * 2049];

    const float4* x4 = (const float4*)x;
    const float4* t4 = (const float4*)t;
    const int n4 = n >> 2;
    const int S = gridDim.x * 256;
    const int lane = threadIdx.x & 63;
    const int wid  = threadIdx.x >> 6;
    uint32_t* wseg = cand1 + (size_t)(blockIdx.x * 4 + wid) * (size_t)segw;
    uint32_t wcur = 0;   // wave-uniform segment cursor (no atomics)

    // block-uniform count of full 4x-unrolled batches (appends use wave-wide
    // shfl scans, so the unrolled loop must be wave-uniform)
    int M4 = 0;
    {
        long rem = (long)n4 - 1 - (long)(blockIdx.x * 256 + 255);
        if (rem >= 0) {
            long T = rem / S;
            if (T >= 3) M4 = (int)((T - 3) / 4 + 1);
        }
    }
    int i = blockIdx.x * 256 + threadIdx.x;

    for (int b = 0; b < M4; ++b, i += 4 * S) {   // 8 independent 16B loads in flight
        float4 xa = x4[i], xb = x4[i + S], xc = x4[i + 2 * S], xd = x4[i + 3 * S];
        float4 ta = t4[i], tb = t4[i + S], tc = t4[i + 2 * S], td = t4[i + 3 * S];
        uint32_t u0, u1, u2, u3, u4_, u5, u6, u7, u8, u9, uA, uB, uC, uD, uE, uF;
        uint32_t ca = quad_u_cls(my, xa, ta, u0, u1, u2, u3);
        uint32_t cb = quad_u_cls(my, xb, tb, u4_, u5, u6, u7);
        uint32_t cc = quad_u_cls(my, xc, tc, u8, u9, uA, uB);
        uint32_t cd = quad_u_cls(my, xd, td, uC, uD, uE, uF);
        cmap[i]         = (uint8_t)ca;
        cmap[i + S]     = (uint8_t)cb;
        cmap[i + 2 * S] = (uint8_t)cc;
        cmap[i + 3 * S] = (uint8_t)cd;
        uint32_t m = (u0 != 0) + (u1 != 0) + (u2 != 0) + (u3 != 0)
                   + (u4_ != 0) + (u5 != 0) + (u6 != 0) + (u7 != 0)
                   + (u8 != 0) + (u9 != 0) + (uA != 0) + (uB != 0)
                   + (uC != 0) + (uD != 0) + (uE != 0) + (uF != 0);
        uint32_t excl, tot;
        wscan(m, lane, excl, tot);
        uint32_t p = wcur + excl;
        if (u0)  wseg[p++] = u0;
        if (u1)  wseg[p++] = u1;
        if (u2)  wseg[p++] = u2;
        if (u3)  wseg[p++] = u3;
        if (u4_) wseg[p++] = u4_;
        if (u5)  wseg[p++] = u5;
        if (u6)  wseg[p++] = u6;
        if (u7)  wseg[p++] = u7;
        if (u8)  wseg[p++] = u8;
        if (u9)  wseg[p++] = u9;
        if (uA)  wseg[p++] = uA;
        if (uB)  wseg[p++] = uB;
        if (uC)  wseg[p++] = uC;
        if (uD)  wseg[p++] = uD;
        if (uE)  wseg[p++] = uE;
        if (uF)  wseg[p++] = uF;
        wcur += tot;
    }

    // masked single-quad remainder (wave-uniform loop via __any)
    for (; __any(i < n4); i += S) {
        const bool act = i < n4;
        float4 xa = act ? x4[i] : make_float4(0.f, 0.f, 0.f, 0.f);
        float4 ta = act ? t4[i] : make_float4(0.f, 0.f, 0.f, 0.f);
        uint32_t u0, u1, u2, u3;
        uint32_t ca = quad_u_cls(my, xa, ta, u0, u1, u2, u3);
        if (act) cmap[i] = (uint8_t)ca;
        uint32_t m = (u0 != 0) + (u1 != 0) + (u2 != 0) + (u3 != 0);
        uint32_t excl, tot;
        wscan(m, lane, excl, tot);
        uint32_t p = wcur + excl;
        if (u0) wseg[p++] = u0;
        if (u1) wseg[p++] = u1;
        if (u2) wseg[p++] = u2;
        if (u3) wseg[p++] = u3;
        wcur += tot;
    }

    // n % 4 tail (block 0 only; <4 elems; no cmap — k_final reads t for tail)
    if (blockIdx.x == 0) {
        int j = (n4 << 2) + threadIdx.x;
        const bool act = j < n;
        float xx = act ? x[j] : 0.0f;
        float tt = act ? t[j] : 0.0f;
        uint32_t u0 = (tt < 0.0f) ? xform(__float_as_uint(xx)) : 0u;
        if (u0) atomicAdd(&my[u0 >> 21], 1u);
        uint32_t excl, tot;
        wscan(u0 != 0 ? 1u : 0u, lane, excl, tot);
        if (u0) wseg[wcur + excl] = u0;
        wcur += tot;
    }

    if (lane == 0) wvcnt[blockIdx.x * 4 + wid] = wcur;

    __syncthreads();
    // merge into 8-way replicated global hist: spreads the ~2M RMWs across
    // 8x the cache lines (was: all blocks onto one 8 KB hist -> per-line
    // serialization, the R5 ping-pong pattern in disguise)
    uint32_t* hmine = hrep + (size_t)(blockIdx.x & (HREP - 1)) * 2048;
    for (int b2 = threadIdx.x; b2 < 2048; b2 += 256) {
        uint32_t c = lh[b2] + lh[2049 + b2];
        if (c) atomicAdd(&hmine[b2], c);
    }
}

// ---------------- s1: 1 block, sum replicas, pick 11-bit prefix ----------------
__global__ __launch_bounds__(256) void s1_scan(
        const uint32_t* __restrict__ hrep, SelState* __restrict__ st,
        const int* __restrict__ kptr) {
    __shared__ uint32_t part[256];
    const int tid = threadIdx.x;
    uint32_t cnt[8];
    uint32_t lsum = 0;
#pragma unroll
    for (int j = 0; j < 8; ++j) {
        uint32_t c = 0;
#pragma unroll
        for (int r = 0; r < HREP; ++r) c += hrep[r * 2048 + tid * 8 + j];
        cnt[j] = c;
        lsum += c;
    }
    part[tid] = lsum;
    __syncthreads();
    for (int off = 1; off < 256; off <<= 1) {   // inclusive suffix sum
        uint32_t add = (tid + off < 256) ? part[tid + off] : 0u;
        __syncthreads();
        part[tid] += add;
        __syncthreads();
    }
    const uint32_t total = part[0];
    int kk = *kptr;
    uint32_t k = (kk > 0) ? (uint32_t)kk : 0u;
    if (k == 0u) {   // keep all negatives
        if (tid == 0) { st->u_kth = 0xFFFFFFFFu; st->thr_nl = __int_as_float(0x7F800000); st->done = 1u; }
        return;
    }
    if (k > total) { // drop all negatives
        if (tid == 0) { st->u_kth = 0u; st->thr_nl = 0.0f; st->done = 1u; }
        return;
    }
    uint32_t A = (tid < 255) ? part[tid + 1] : 0u;  // strictly-above count
#pragma unroll
    for (int j = 7; j >= 0; --j) {
        uint32_t c = cnt[j];
        if (A < k && k <= A + c) {   // exactly one (thread,bin)
            st->prefix1 = (uint32_t)(tid * 8 + j);
            st->k1rem = k - A;       // done stays 0 (memset)
        }
        A += c;
    }
}

// ---------- k2_sel21: filter cand1 by prefix1 -> scattered 2^21-bin hist ----------
__global__ __launch_bounds__(256) void k2_sel21(
        const uint32_t* __restrict__ cand1, const uint32_t* __restrict__ wvcnt,
        uint32_t* __restrict__ h21, const SelState* __restrict__ st, int segw) {
    __shared__ uint32_t s_pref, s_done;
    if (threadIdx.x == 0) { s_pref = st->prefix1; s_done = st->done; }
    __syncthreads();
    if (s_done) return;
    const uint32_t pref = s_pref;
    const int lane = threadIdx.x & 63;
    const int wid  = threadIdx.x >> 6;
    const int sidx = blockIdx.x * 4 + wid;   // same block index as k1 wrote:
    const uint32_t cnt = wvcnt[sidx];        // likely same-XCD L2-hot read
    const uint4* b4 = (const uint4*)(cand1 + (size_t)sidx * (size_t)segw);
    const uint32_t iters = (cnt + 255u) >> 8;
    for (uint32_t it = 0; it < iters; ++it) {
        const uint32_t e0 = it * 256u + (uint32_t)lane * 4u;
        uint4 v = b4[it * 64u + (uint32_t)lane];   // in-bounds: cnt<=256*Q<=segw-4
        if (e0 + 0u < cnt && (v.x >> 21) == pref) atomicAdd(&h21[v.x & 0x1FFFFFu], 1u);
        if (e0 + 1u < cnt && (v.y >> 21) == pref) atomicAdd(&h21[v.y & 0x1FFFFFu], 1u);
        if (e0 + 2u < cnt && (v.z >> 21) == pref) atomicAdd(&h21[v.z & 0x1FFFFFu], 1u);
        if (e0 + 3u < cnt && (v.w >> 21) == pref) atomicAdd(&h21[v.w & 0x1FFFFFu], 1u);
    }
}

// ---------------- scan2a: per-chunk sums of hist21 (1024 chunks x 2048 bins) ----------------
__global__ __launch_bounds__(256) void scan2a(
        const uint32_t* __restrict__ h21, uint32_t* __restrict__ csums,
        const SelState* __restrict__ st) {
    __shared__ uint32_t red[256];
    __shared__ uint32_t s_done;
    if (threadIdx.x == 0) s_done = st->done;
    __syncthreads();
    if (s_done) return;   // csums unread on this path
    const uint4* b4 = (const uint4*)(h21 + (size_t)blockIdx.x * 2048);
    uint32_t s = 0;
    for (int j = threadIdx.x; j < 512; j += 256) {
        uint4 v = b4[j];
        s += v.x + v.y + v.z + v.w;
    }
    red[threadIdx.x] = s;
    __syncthreads();
    for (int off = 128; off > 0; off >>= 1) {
        if (threadIdx.x < off) red[threadIdx.x] += red[threadIdx.x + off];
        __syncthreads();
    }
    if (threadIdx.x == 0) csums[blockIdx.x] = red[0];
}

// ---------------- scan2b: 1 block, pick chunk then bin -> u_kth ----------------
__global__ __launch_bounds__(256) void scan2b(
        const uint32_t* __restrict__ h21, const uint32_t* __restrict__ csums,
        SelState* __restrict__ st) {
    __shared__ uint32_t part[256];
    __shared__ uint32_t sel[2];
    __shared__ SelState sst;
    const int tid = threadIdx.x;
    if (tid == 0) sst = *st;
    __syncthreads();
    if (sst.done) return;
    const uint32_t k = sst.k1rem;

    // stage 1: 1024 chunk sums, 4 per thread
    uint32_t c4[4];
    uint32_t lsum = 0;
#pragma unroll
    for (int j = 0; j < 4; ++j) { c4[j] = csums[tid * 4 + j]; lsum += c4[j]; }
    part[tid] = lsum;
    __syncthreads();
    for (int off = 1; off < 256; off <<= 1) {
        uint32_t add = (tid + off < 256) ? part[tid + off] : 0u;
        __syncthreads();
        part[tid] += add;
        __syncthreads();
    }
    uint32_t A = (tid < 255) ? part[tid + 1] : 0u;
#pragma unroll
    for (int j = 3; j >= 0; --j) {
        uint32_t c = c4[j];
        if (A < k && k <= A + c) { sel[0] = (uint32_t)(tid * 4 + j); sel[1] = k - A; }
        A += c;
    }
    __syncthreads();
    const uint32_t chunk = sel[0];
    const uint32_t k2 = sel[1];
    __syncthreads();

    // stage 2: 2048 bins of the chosen chunk, 8 per thread
    const uint32_t* base = h21 + (size_t)chunk * 2048;
    uint32_t b8[8];
    lsum = 0;
#pragma unroll
    for (int j = 0; j < 8; ++j) { b8[j] = base[tid * 8 + j]; lsum += b8[j]; }
    part[tid] = lsum;
    __syncthreads();
    for (int off = 1; off < 256; off <<= 1) {
        uint32_t add = (tid + off < 256) ? part[tid + off] : 0u;
        __syncthreads();
        part[tid] += add;
        __syncthreads();
    }
    A = (tid < 255) ? part[tid + 1] : 0u;
#pragma unroll
    for (int j = 7; j >= 0; --j) {
        uint32_t c = b8[j];
        if (A < k2 && k2 <= A + c) {
            uint32_t u = (sst.prefix1 << 21) | (chunk * 2048u + (uint32_t)(tid * 8 + j));
            st->u_kth = u;
            st->thr_nl = neg_loss_precise(unxform(u), -1.0f);  // t = -1 exactly
            st->done = 1u;
        }
        A += c;
    }
}

// ---------------- final: fast-math values, bit-exact mask, class map ----------------
__device__ __forceinline__ float fin1c(float xx, uint32_t cls, uint32_t ukth, float thr) {
    float lp = __logf(1.0f + __expf(-fabsf(xx)));   // HW exp/log
    float v = 0.0f;
    if (cls == 1u) {                    // t = +1
        v = (fmaxf(xx, 0.0f) - xx) + lp;
    } else if (cls == 2u) {             // t = -1
        uint32_t u = xform(__float_as_uint(xx));
        bool keep = u < ukth;
        if (keep && (ukth - u) < GUARD)             // ~0 lanes hit this
            keep = neg_loss_precise(xx, -1.0f) < thr;
        if (keep) v = (fmaxf(-xx, 0.0f) + xx) + lp;
    }
    return v;
}

__device__ __forceinline__ float4 fin_quadc(float4 xv, uint32_t cb, uint32_t ukth, float thr) {
    float4 r;
    r.x = fin1c(xv.x, cb & 3u, ukth, thr);
    r.y = fin1c(xv.y, (cb >> 2) & 3u, ukth, thr);
    r.z = fin1c(xv.z, (cb >> 4) & 3u, ukth, thr);
    r.w = fin1c(xv.w, (cb >> 6) & 3u, ukth, thr);
    return r;
}

// tail helper: original t-based path
__device__ __forceinline__ float fin1t(float xx, float tt, uint32_t ukth, float thr) {
    float lp = __logf(1.0f + __expf(-fabsf(xx)));
    float v = 0.0f;
    if (tt > 0.0f) {
        v = fmaxf(xx, 0.0f) - xx * tt + lp;
    } else if (tt < 0.0f) {
        uint32_t u = xform(__float_as_uint(xx));
        bool keep = u < ukth;
        if (keep && (ukth - u) < GUARD)
            keep = neg_loss_precise(xx, tt) < thr;
        if (keep) v = fmaxf(-xx, 0.0f) - xx * tt + lp;
    }
    return v;
}

__global__ __launch_bounds__(256) void k_final(
        const float* __restrict__ x, const float* __restrict__ t,
        const uint8_t* __restrict__ cmap, const SelState* __restrict__ st,
        float* __restrict__ out, int n) {
    const uint32_t ukth = st->u_kth;
    const float thr = st->thr_nl;
    const float4* x4 = (const float4*)x;
    float4* o4 = (float4*)out;
    const int n4 = n >> 2;
    const int S = gridDim.x * 256;
    int i = blockIdx.x * 256 + threadIdx.x;
    for (; i + 3 * S < n4; i += 4 * S) {
        float4 xa = x4[i], xb = x4[i + S], xc = x4[i + 2 * S], xd = x4[i + 3 * S];
        uint32_t ca = cmap[i], cb = cmap[i + S], cc = cmap[i + 2 * S], cd = cmap[i + 3 * S];
        o4[i]         = fin_quadc(xa, ca, ukth, thr);
        o4[i + S]     = fin_quadc(xb, cb, ukth, thr);
        o4[i + 2 * S] = fin_quadc(xc, cc, ukth, thr);
        o4[i + 3 * S] = fin_quadc(xd, cd, ukth, thr);
    }
    for (; i < n4; i += S) {
        float4 xa = x4[i];
        uint32_t ca = cmap[i];
        o4[i] = fin_quadc(xa, ca, ukth, thr);
    }
    if (blockIdx.x == 0) {  // n % 4 tail: no cmap — use t directly
        for (int j = (n4 << 2) + threadIdx.x; j < n; j += 256) {
            out[j] = fin1t(x[j], t[j], ukth, thr);
        }
    }
}

extern "C" void kernel_launch(void* const* d_in, const int* in_sizes, int n_in,
                              void* d_out, int out_size, void* d_ws, size_t ws_size,
                              hipStream_t stream) {
    const float* x = (const float*)d_in[0];
    const float* t = (const float*)d_in[1];
    const int* kptr = (const int*)d_in[2];
    float* out = (float*)d_out;
    const int n = in_sizes[0];
    if (n <= 0) return;

    const int n4 = n >> 2;
    int work = (n4 + 255) / 256;
    if (work < 1) work = 1;
    int grid = work < 1024 ? work : 1024;   // 4 blocks/CU
    const int S = grid * 256;
    const int Q = (n4 + S - 1) / S;          // max quads per thread
    const int segw = 256 * Q + 4;            // words per wave segment (16B mult)
    const int nseg = grid * 4;               // <= 4096

    char* ws = (char*)d_ws;
    uint32_t* hrep  = (uint32_t*)(ws + 0);          // 8 x 2048 u32 (64 KB)
    SelState* st    = (SelState*)(ws + 65536);
    uint32_t* h21   = (uint32_t*)(ws + 65792);      // 2^21 u32 (8 MB)
    size_t csoff = 65792 + ((size_t)1u << 21) * 4u; // 8454400
    uint32_t* csums = (uint32_t*)(ws + csoff);      // 1024 u32 (written before read)
    uint32_t* wvcnt = (uint32_t*)(ws + csoff + 4096);  // 16 KB reserved (always written)
    size_t cmoff = csoff + 4096 + 16384;
    uint8_t*  cmap  = (uint8_t*)(ws + cmoff);       // n4 bytes
    size_t c1off = (cmoff + (size_t)n4 + 255) & ~(size_t)255;
    uint32_t* cand1 = (uint32_t*)(ws + c1off);      // nseg*segw u32 (~42 MB)

    // zero hrep + state + hist21 in one memset (~8.45 MB ≈ 1.3 µs)
    hipMemsetAsync(d_ws, 0, csoff, stream);

    k1_hist <<<grid, 256, 0, stream>>>(x, t, hrep, cand1, wvcnt, cmap, n, segw);
    s1_scan <<<1, 256, 0, stream>>>(hrep, st, kptr);
    k2_sel21<<<grid, 256, 0, stream>>>(cand1, wvcnt, h21, st, segw);
    scan2a  <<<1024, 256, 0, stream>>>(h21, csums, st);
    scan2b  <<<1, 256, 0, stream>>>(h21, csums, st);
    k_final <<<grid, 256, 0, stream>>>(x, t, cmap, st, out, n);
}